// Round 13
// baseline (2752.356 us; speedup 1.0000x reference)
//
#include <hip/hip_runtime.h>
#include <math.h>

#define TT 6
#define FC 24
#define KN 35
#define HW 65536
#define NPIX (TT*HW)   // 393216
#define CPB 16         // columns per block in col-FFT

// padded plane geometry: 5-halo on all sides, stride 272 (16B-chunk friendly)
#define VSTRIDE 272
#define VROWS   266
#define VPLANE  (VROWS*VSTRIDE)          // 72352 elems per plane
#define VIOFF   (5*VSTRIDE + 5)          // interior origin
#define HALO_PER_PLANE 6816              // float2-plane halo positions
#define WQ_PER_LAYER  (3*11*512)         // fwd B-frags: 16896 bf16/layer
#define WQA_PER_LAYER (24*12*4*16)       // adj weights: 18432 bf16/layer
#define NBFPLANES 576                    // Vbf: 2 parity x 2 part x 6 t x 24 f
#define PPBF 7072                        // bf16-plane halo positions (incl. padded col 260)

typedef float v2f __attribute__((ext_vector_type(2)));
typedef float v4f __attribute__((ext_vector_type(4)));
typedef short short8 __attribute__((ext_vector_type(8)));
typedef int  v4i  __attribute__((ext_vector_type(4)));
typedef v4i  v4i_u __attribute__((aligned(4)));   // 16B vector load, 4B alignment

__device__ inline float2 cmulf(float2 a, float2 b){
    return make_float2(a.x*b.x - a.y*b.y, a.x*b.y + a.y*b.x);
}

__device__ inline void gl_lds16(const void* g, void* l){
    __builtin_amdgcn_global_load_lds((const __attribute__((address_space(1))) unsigned int*)g,
                                     (__attribute__((address_space(3))) unsigned int*)l,
                                     16, 0, 0);
}

__device__ __host__ inline unsigned short f2bf(float x){
    unsigned u = __float_as_uint(x);
    unsigned r = (u + 0x7FFFu + ((u >> 16) & 1u)) >> 16;
    return (unsigned short)r;
}

// ---------------- halo zero: 5-wide borders of the 6 float2 Xpad planes ---------
__global__ void halo_zero_kernel(float2* base){
    int gid = blockIdx.x*256 + threadIdx.x;
    if (gid >= TT*HALO_PER_PLANE) return;
    int p = gid / HALO_PER_PLANE;
    int i = gid - p*HALO_PER_PLANE;
    int row, col;
    if (i < 2720){
        row = i / 272; col = i - row*272;
        if (row >= 5) row += 256;
    } else {
        int j = i - 2720;
        row = 5 + j/16;
        col = j & 15;
        if (col >= 5) col += 256;
    }
    base[(long)p*VPLANE + (long)row*VSTRIDE + col] = make_float2(0.f, 0.f);
}

// ---------------- halo zero for the 576 bf16 V planes (+ padded col 260) --------
__global__ void halo_zero_bf16_kernel(unsigned short* base){
    int gid = blockIdx.x*256 + threadIdx.x;
    if (gid >= NBFPLANES*PPBF) return;
    int p = gid / PPBF;
    int i = gid - p*PPBF;
    int row, col;
    if (i < 2720){                   // top 5 + bottom 5 full rows
        row = i / 272; col = i - row*272;
        if (row >= 5) row += 256;
    } else {                         // middle rows: cols 0..4 and 260..271
        int j = i - 2720;
        row = 5 + j/17;
        int cc = j % 17;
        col = (cc < 5) ? cc : cc + 255;   // 5..16 -> 260..271
    }
    base[(long)p*VPLANE + (long)row*VSTRIDE + col] = 0;
}

// ---------------- reduction: sum|X|^2 and sum(mask) ----------------
__global__ void reduce_kernel(const float* xr, const float* xi, const float* mask, float* sums){
    __shared__ float s1[256], s2[256];
    int tid = threadIdx.x;
    int gid = blockIdx.x*256 + tid;
    float a = 0.f, b = 0.f;
    for (int i = gid; i < NPIX; i += gridDim.x*256) a += xr[i]*xr[i] + xi[i]*xi[i];
    for (int i = gid; i < TT*256; i += gridDim.x*256) b += mask[i];
    s1[tid]=a; s2[tid]=b; __syncthreads();
    for (int off=128; off>0; off>>=1){
        if (tid<off){ s1[tid]+=s1[tid+off]; s2[tid]+=s2[tid+off]; }
        __syncthreads();
    }
    if (tid==0){ atomicAdd(&sums[0], s1[0]); atomicAdd(&sums[1], s2[0]); }
}

// ---------------- normalize: Xks = (xr + i xi)/norm ----------------
__global__ void normalize_kernel(const float* xr, const float* xi, const float* sums, float2* Xks){
    int i = blockIdx.x*256 + threadIdx.x;
    float inv = rsqrtf(sums[0]/sums[1]);
    Xks[i] = make_float2(xr[i]*inv, xi[i]*inv);
}

// ---------------- fwd MFMA weight prepack: B-frag order, bf16 -------------------
__global__ void prepack_wfrag_kernel(const float* kr, const float* ki, unsigned short* Wq){
    int idx = blockIdx.x*256 + threadIdx.x;
    if (idx >= 8*WQ_PER_LAYER) return;
    int j    = idx & 7;
    int lane = (idx >> 3) & 63;
    int ky   = (idx >> 9) % 11;
    int nt   = (idx / (512*11)) % 3;
    int l    =  idx / (512*11*3);
    int quad = lane >> 4;
    int k    = quad*8 + j;
    int part = k >> 4;
    int kx   = k & 15;
    int n    = nt*16 + (lane & 15);
    int f    = n >> 1, comp = n & 1;
    float v = 0.f;
    if (kx <= 10){
        long wi = ((long)(l*24+f))*121 + ky*11 + kx;
        float wr = kr[wi], wim = ki[wi];
        v = (comp == 0) ? (part == 0 ? wr  : -wim)
                        : (part == 0 ? wim :  wr );
    }
    Wq[idx] = f2bf(v);
}

// ---------------- adj MFMA weight prepack: [l][f][kyrow12][s4][kx16] bf16 --------
// kyrow 0 = zero row; kyrow 1..11 = ky 0..10 (weights pre-flipped).
// s = comp*2+part: 0->wr, 1->wi, 2->-wi, 3->wr
__global__ void prepack_wadj_kernel(const float* kr, const float* ki, unsigned short* Wqa){
    int idx = blockIdx.x*256 + threadIdx.x;
    if (idx >= 8*WQA_PER_LAYER) return;
    int kx    = idx & 15;
    int s     = (idx >> 4) & 3;
    int kyrow = (idx >> 6) % 12;
    int f     = ((idx >> 6) / 12) % 24;
    int l     = idx / WQA_PER_LAYER;
    float v = 0.f;
    if (kyrow > 0 && kx <= 10){
        int ky = kyrow - 1;
        long src = (long)(l*24 + f)*121 + (120 - (ky*11 + kx));   // spatial flip
        float wr = kr[src], wi = ki[src];
        v = (s == 0) ? wr : (s == 1) ? wi : (s == 2) ? -wi : wr;
    }
    Wqa[idx] = f2bf(v);
}

// ---------------- cast Ximg -> bf16 planes: [copy(2)][part(2)][t(6)] ------------
__global__ void cast_bf16_kernel(const float2* __restrict__ Xpad, unsigned short* __restrict__ Xbf){
    int idx = blockIdx.x*256 + threadIdx.x;
    if (idx >= TT*VPLANE) return;
    int t = idx / VPLANE;
    int p = idx - t*VPLANE;
    float2 a = Xpad[(long)t*VPLANE + p];
    float2 b = Xpad[(long)t*VPLANE + p + 1];
    Xbf[((long)(0*6+t))*VPLANE + p]  = f2bf(a.x);
    Xbf[((long)(1*6+t))*VPLANE + p]  = f2bf(a.y);
    Xbf[((long)(2*6+t))*VPLANE + p]  = f2bf(b.x);
    Xbf[((long)(3*6+t))*VPLANE + p]  = f2bf(b.y);
}

// ---------------- FFT row pass (init only) ----------------
__global__ void fft_row_kernel(const float2* __restrict__ in, float2* __restrict__ out,
                               float dir, float scale){
    __shared__ float2 lds[2][256];
    __shared__ float2 tw[128];
    int tid = threadIdx.x;
    int line = tid >> 7;
    int j = tid & 127;
    if (tid < 128){
        float s, c;
        sincosf(dir * 6.283185307179586f * (float)tid / 256.0f, &s, &c);
        tw[tid] = make_float2(c, s);
    }
    long gline = (long)blockIdx.x*2 + line;
    const float2* src = in + gline*256;
    {
        float sg = (j & 1) ? -1.f : 1.f;
        float2 a = src[j];
        float2 b = src[j+128];
        lds[line][j]     = make_float2(a.x*sg, a.y*sg);
        lds[line][j+128] = make_float2(b.x*sg, b.y*sg);
    }
    __syncthreads();
    for (int s = 0; s < 8; s++){
        int half = 128 >> s;
        int pos = j & (half-1);
        int grp = j >> (7-s);
        int i0 = (grp << (8-s)) + pos;
        int i1 = i0 + half;
        float2 u = lds[line][i0], v = lds[line][i1];
        float2 w = tw[pos << s];
        lds[line][i0] = make_float2(u.x+v.x, u.y+v.y);
        float2 d = make_float2(u.x-v.x, u.y-v.y);
        lds[line][i1] = cmulf(d, w);
        __syncthreads();
    }
    float2* dst = out + gline*256;
    {
        int k = j;
        float sg = (k & 1) ? -scale : scale;
        float2 v = lds[line][__brev((unsigned)k) >> 24];
        dst[k] = make_float2(v.x*sg, v.y*sg);
        k = j + 128;
        sg = (k & 1) ? -scale : scale;
        v = lds[line][__brev((unsigned)k) >> 24];
        dst[k] = make_float2(v.x*sg, v.y*sg);
    }
}

// ---------------- FFT col pass (init only): writes Xpad (*k0) and G ------------
__global__ void fft_col_kernel(const float2* __restrict__ in, float2* __restrict__ Xpad,
                               float2* __restrict__ G, float dir, float scale, const float* k0){
    __shared__ float2 lds[256][CPB+1];
    __shared__ float2 tw[128];
    int tid = threadIdx.x;
    if (tid < 128){
        float s, c;
        sincosf(dir * 6.283185307179586f * (float)tid / 256.0f, &s, &c);
        tw[tid] = make_float2(c, s);
    }
    int t  = blockIdx.x / (256/CPB);
    int w0 = (blockIdx.x % (256/CPB)) * CPB;
    const float2* src = in + (long)t*HW;
    int c  = tid & (CPB-1);
    int h0 = tid >> 4;
    for (int i = 0; i < 16; i++){
        int h = h0 + 16*i;
        float2 v = src[h*256 + w0 + c];
        float sg = (h & 1) ? -1.f : 1.f;
        lds[h][c] = make_float2(v.x*sg, v.y*sg);
    }
    __syncthreads();
    int jb = tid >> 4;
    for (int s = 0; s < 8; s++){
        int half = 128 >> s;
        for (int i = 0; i < 8; i++){
            int j = jb + 16*i;
            int pos = j & (half-1);
            int grp = j >> (7-s);
            int i0 = (grp << (8-s)) + pos;
            int i1 = i0 + half;
            float2 u = lds[i0][c], v = lds[i1][c];
            float2 w = tw[pos << s];
            lds[i0][c] = make_float2(u.x+v.x, u.y+v.y);
            float2 d = make_float2(u.x-v.x, u.y-v.y);
            lds[i1][c] = cmulf(d, w);
        }
        __syncthreads();
    }
    float kk = *k0;
    for (int i = 0; i < 16; i++){
        int k = h0 + 16*i;
        float2 v = lds[__brev((unsigned)k) >> 24][c];
        float sg = (k & 1) ? -scale : scale;
        float2 g = make_float2(v.x*sg, v.y*sg);
        G[(long)t*HW + k*256 + w0 + c] = g;
        Xpad[(long)t*VPLANE + VIOFF + k*VSTRIDE + w0 + c] = make_float2(g.x*kk, g.y*kk);
    }
}

// ---------------- MFMA forward conv (1->24) + fused spline act ------------------
// Writes V as bf16 split planes [parity(2)][part(2)][t][f] (copy1[w] = orig[w+1]).
__global__ __launch_bounds__(256) void conv_fwd_mfma_kernel(
        const unsigned short* __restrict__ Xbf, const unsigned short* __restrict__ Wq,
        const float* __restrict__ knots, unsigned short* __restrict__ Vbf){
    __shared__ __align__(16) unsigned short wlds[WQ_PER_LAYER];
    int tid = threadIdx.x;
    {
        int wv = tid >> 6, ln = tid & 63;
        #pragma unroll
        for (int r = 0; r < 9; r++){
            int c = r*256 + wv*64 + ln;
            if (c < 2112)
                gl_lds16(Wq + (long)c*8, (char*)wlds + (unsigned)(r*256 + wv*64)*16u);
        }
    }
    int h  = blockIdx.y;
    int w0 = blockIdx.x*64;
    int lane = tid & 63, wave = tid >> 6;
    int half = wave >> 1, parity = wave & 1;
    int quad = lane >> 4, l15 = lane & 15;
    int part = quad >> 1, kx0 = (quad & 1)*8;
    int col0 = half*32 + 2*l15 + kx0;

    __syncthreads();

    v4f D[3][6];
    #pragma unroll
    for (int nt = 0; nt < 3; nt++)
        #pragma unroll
        for (int t = 0; t < 6; t++) D[nt][t] = (v4f)(0.f);

    const short8* wl = (const short8*)wlds;
    #pragma unroll
    for (int t = 0; t < 6; t++){
        const unsigned short* ab = Xbf + ((long)((parity*2 + part)*6 + t))*VPLANE
                                       + (long)h*272 + w0 + col0;
        #pragma unroll
        for (int ky = 0; ky < 11; ky++){
            union { v4i i; short8 s; } ua;
            ua.i = *(const v4i_u*)(ab + (long)ky*272);
            short8 a = ua.s;
            #pragma unroll
            for (int nt = 0; nt < 3; nt++){
                short8 b = wl[(nt*11 + ky)*64 + lane];
                D[nt][t] = __builtin_amdgcn_mfma_f32_16x16x32_bf16(a, b, D[nt][t], 0, 0, 0);
            }
        }
    }

    float aout[3][4];
    #pragma unroll
    for (int nt = 0; nt < 3; nt++){
        int f = (nt*16 + l15) >> 1;
        #pragma unroll
        for (int r = 0; r < 4; r++){
            float s = 0.f;
            #pragma unroll
            for (int t = 0; t < 6; t++) s = fmaf(D[nt][t][r], D[nt][t][r], s);
            s += __shfl_xor(s, 1, 64);
            float act_in = sqrtf(s) * (1.0f/6.0f);
            float pos = fminf(fmaxf(act_in * 34.0f, 0.0f), 34.0f);
            int i0 = (int)pos; if (i0 > 33) i0 = 33;
            float frac = pos - (float)i0;
            float k0v = knots[i0*24 + f];
            float k1v = knots[(i0+1)*24 + f];
            aout[nt][r] = k0v*(1.0f - frac) + k1v*frac;
        }
    }

    float* tb = (float*)wlds;
    #pragma unroll
    for (int t = 0; t < 6; t++){
        __syncthreads();
        #pragma unroll
        for (int nt = 0; nt < 3; nt++)
            #pragma unroll
            for (int r = 0; r < 4; r++){
                int px = half*32 + 2*(quad*4 + r) + parity;
                tb[px*50 + nt*16 + l15] = D[nt][t][r] * aout[nt][r];
            }
        __syncthreads();
        #pragma unroll
        for (int q = 0; q < 6; q++){
            int idx = q*256 + tid;
            int f = idx >> 6, px = idx & 63;
            float2 val = *(const float2*)&tb[px*50 + 2*f];
            long off = VIOFF + (long)h*VSTRIDE + (w0 + px);
            unsigned short vr = f2bf(val.x), vi = f2bf(val.y);
            Vbf[((long)((0*6 + t)*24 + f))*VPLANE + off]      = vr;   // p0 part0
            Vbf[((long)((1*6 + t)*24 + f))*VPLANE + off]      = vi;   // p0 part1
            Vbf[((long)((2*6 + t)*24 + f))*VPLANE + off - 1]  = vr;   // p1 part0 at c-1
            Vbf[((long)((3*6 + t)*24 + f))*VPLANE + off - 1]  = vi;   // p1 part1 at c-1
        }
    }
}

// ---------------- MFMA adjoint conv 24->1, dh-expanded implicit GEMM ------------
// Wave-tile: 8 output rows (dh) x 16 cols. M=16 w-px, N=16=(dh,comp), K=32=(part,kx16)
// per (f, ky' 0..17). A: V bf16 planes from global (parity-aligned). B: compact LDS
// weights [f][kyrow][s][kx16], zero row for ky'-dh outside [0,10].
__global__ __launch_bounds__(256) void conv_adj_mfma_kernel(
        const unsigned short* __restrict__ Vbf, const unsigned short* __restrict__ Wqa,
        float* __restrict__ rg){
    __shared__ __align__(16) unsigned short wlds[WQA_PER_LAYER];   // 36864 B
    int tid = threadIdx.x;
    {
        int wv = tid >> 6, ln = tid & 63;
        #pragma unroll
        for (int r = 0; r < 9; r++){
            int c = r*256 + wv*64 + ln;   // 0..2303, exactly covers 2304 chunks
            gl_lds16(Wqa + (long)c*8, (char*)wlds + (unsigned)(r*256 + wv*64)*16u);
        }
    }
    int wave = tid >> 6, lane = tid & 63;
    int tile = blockIdx.x*4 + wave;      // 0..3071
    int t    = tile >> 9;
    int rem  = tile & 511;
    int w0   = (rem & 15) * 16;
    int h0   = (rem >> 4) * 8;
    int l15 = lane & 15, quad = lane >> 4;
    int part = quad >> 1, kx0 = (quad & 1)*8;
    int dh = l15 >> 1, comp = l15 & 1;
    int sbase = (comp*2 + part)*16 + kx0;        // elem offset within [kyrow] row
    int c0 = w0 + l15 + kx0 - 5;
    int p  = c0 & 1;
    const unsigned short* abase = Vbf + ((long)(((p*2 + part)*6 + t)*24))*VPLANE
                                      + (long)h0*272 + (c0 - p + 5);
    __syncthreads();   // weights staged

    v4f D = (v4f)(0.f);
    #pragma unroll 1
    for (int f = 0; f < 24; f++){
        const unsigned short* ap = abase + (long)f*VPLANE;
        int fbase = f*768 + sbase;
        #pragma unroll
        for (int kyp = 0; kyp < 18; kyp++){
            union { v4i i; short8 s; } ua;
            ua.i = *(const v4i_u*)(ap + (long)kyp*272);
            int ky = kyp - dh;
            int kyrow = ((unsigned)ky <= 10u) ? (ky + 1) : 0;
            short8 b = *(const short8*)(&wlds[fbase + kyrow*64]);
            D = __builtin_amdgcn_mfma_f32_16x16x32_bf16(ua.s, b, D, 0, 0, 0);
        }
    }
    // D: row m=quad*4+reg = w-offset, col n=l15=(dh,comp)
    float* out = rg + (long)t*HW*2;
    #pragma unroll
    for (int r = 0; r < 4; r++){
        int w = w0 + quad*4 + r;
        out[((long)(h0 + dh)*256 + w)*2 + comp] = D[r];
    }
}

// ---------------- fused data-consistency + momentum update --------------------
__global__ void dc_update_kernel(float2* __restrict__ Xpad, float2* __restrict__ m,
                                 const float2* __restrict__ rg, const float2* __restrict__ G,
                                 const float* __restrict__ mask,
                                 const float* __restrict__ alphas, const float* __restrict__ moms,
                                 int l){
    __shared__ float2 lds[2][256];
    __shared__ float2 tw[128];
    int tid = threadIdx.x;
    int line = tid >> 7;
    int j = tid & 127;
    if (tid < 128){
        float s, c;
        sincosf(6.283185307179586f * (float)tid / 256.0f, &s, &c);
        tw[tid] = make_float2(c, s);
    }
    long gl = (long)blockIdx.x*2 + line;
    int t = (int)(gl >> 8);
    int h = (int)(gl & 255);
    float2* src = Xpad + (long)t*VPLANE + VIOFF + (long)h*VSTRIDE;
    float2 xo0, xo1;
    {
        float sg = (j & 1) ? -1.f : 1.f;
        xo0 = src[j]; xo1 = src[j+128];
        lds[line][j]     = make_float2(xo0.x*sg, xo0.y*sg);
        lds[line][j+128] = make_float2(xo1.x*sg, xo1.y*sg);
    }
    __syncthreads();
    for (int s = 0; s < 8; s++){
        int half = 128 >> s;
        int pos = j & (half-1);
        int grp = j >> (7-s);
        int i0 = (grp << (8-s)) + pos;
        int i1 = i0 + half;
        float2 u = lds[line][i0], v = lds[line][i1];
        float2 w = tw[pos << s]; w.y = -w.y;
        lds[line][i0] = make_float2(u.x+v.x, u.y+v.y);
        float2 d = make_float2(u.x-v.x, u.y-v.y);
        lds[line][i1] = cmulf(d, w);
        __syncthreads();
    }
    {
        int k1 = __brev((unsigned)j) >> 24;
        int k2 = __brev((unsigned)(j+128)) >> 24;
        float mv1 = mask[t*256 + k1] * (1.0f/256.0f);
        float mv2 = mask[t*256 + k2] * (1.0f/256.0f);
        float2 a = lds[line][j], b = lds[line][j+128];
        lds[line][j]     = make_float2(a.x*mv1, a.y*mv1);
        lds[line][j+128] = make_float2(b.x*mv2, b.y*mv2);
    }
    __syncthreads();
    for (int s = 0; s < 8; s++){
        int m2 = 1 << s;
        int pos = j & (m2-1);
        int grp = j >> s;
        int i0 = (grp << (s+1)) + pos;
        int i1 = i0 + m2;
        float2 u = lds[line][i0];
        float2 v = cmulf(lds[line][i1], tw[pos << (7-s)]);
        lds[line][i0] = make_float2(u.x+v.x, u.y+v.y);
        lds[line][i1] = make_float2(u.x-v.x, u.y-v.y);
        __syncthreads();
    }
    float a  = alphas[l];
    float mu = moms[l];
    float sg = (j & 1) ? -1.f : 1.f;
    #pragma unroll
    for (int half = 0; half < 2; half++){
        int k = j + half*128;
        long idx = gl*256 + k;
        float2 d = lds[line][k];
        d = make_float2(d.x*sg, d.y*sg);
        float2 g = G[idx];
        float2 r0 = rg[idx];
        float2 grad = make_float2(fmaf(a, d.x - g.x, r0.x), fmaf(a, d.y - g.y, r0.y));
        float2 mm;
        if (l == 0){
            mm = grad;
        } else {
            float2 mv = m[idx];
            mm = make_float2(fmaf(mu, mv.x, grad.x), fmaf(mu, mv.y, grad.y));
        }
        m[idx] = mm;
        float2 xo = half ? xo1 : xo0;
        src[k] = make_float2(xo.x - mm.x, xo.y - mm.y);
    }
}

// ---------------- output: stack(real, imag)*norm ----------------
__global__ void output_kernel(const float2* __restrict__ Xpad, const float* __restrict__ sums,
                              float* __restrict__ out){
    int i = blockIdx.x*256 + threadIdx.x;
    int t = i >> 16;
    int p = i & 65535;
    int h = p >> 8, w = p & 255;
    float norm = sqrtf(sums[0]/sums[1]);
    float2 v = Xpad[(long)t*VPLANE + VIOFF + h*VSTRIDE + w];
    out[2*i]   = v.x * norm;
    out[2*i+1] = v.y * norm;
}

extern "C" void kernel_launch(void* const* d_in, const int* in_sizes, int n_in,
                              void* d_out, int out_size, void* d_ws, size_t ws_size,
                              hipStream_t stream){
    const float* Xr    = (const float*)d_in[0];
    const float* Xi    = (const float*)d_in[1];
    const float* mask  = (const float*)d_in[2];
    const float* kr    = (const float*)d_in[3];
    const float* ki    = (const float*)d_in[4];
    const float* knots = (const float*)d_in[5];
    const float* alph  = (const float*)d_in[6];
    const float* moms  = (const float*)d_in[7];
    const float* k0    = (const float*)d_in[8];

    float* ws   = (float*)d_ws;
    float* sums = ws;                                          // 16 floats
    unsigned short* Wq  = (unsigned short*)(ws + 16);          // 8*16896
    unsigned short* Wqa = Wq  + 8*WQ_PER_LAYER;                // 8*18432
    unsigned short* Xbf = Wqa + 8*WQA_PER_LAYER;               // 24*VPLANE
    float2* mbuf = (float2*)(Xbf + 24*VPLANE);
    float2* G    = mbuf + NPIX;
    float2* rg   = G    + NPIX;                                // also init FFT temp
    float2* Xpad = rg   + NPIX;                                // 6*VPLANE float2
    unsigned short* Vbf = (unsigned short*)(Xpad + TT*VPLANE); // 576*VPLANE bf16
    float2* Xks  = (float2*)Vbf;                               // init-only alias

    const float OS = 1.0f/16.0f;

    hipMemsetAsync(sums, 0, 2*sizeof(float), stream);

    prepack_wfrag_kernel<<<(8*WQ_PER_LAYER + 255)/256, 256, 0, stream>>>(kr, ki, Wq);
    prepack_wadj_kernel<<<(8*WQA_PER_LAYER + 255)/256, 256, 0, stream>>>(kr, ki, Wqa);
    reduce_kernel<<<384, 256, 0, stream>>>(Xr, Xi, mask, sums);
    normalize_kernel<<<NPIX/256, 256, 0, stream>>>(Xr, Xi, sums, Xks);

    // init: Xpad = k2i(Xks)*k0 (padded) ; G = k2i(Xks)
    fft_row_kernel<<<TT*128, 256, 0, stream>>>(Xks, rg, +1.0f, OS);
    fft_col_kernel<<<TT*(256/CPB), 256, 0, stream>>>(rg, Xpad, G, +1.0f, OS, k0);

    // zero halos AFTER init (Xks alias in Vbf region is dead now)
    halo_zero_kernel<<<(TT*HALO_PER_PLANE + 255)/256, 256, 0, stream>>>(Xpad);
    halo_zero_bf16_kernel<<<(NBFPLANES*PPBF + 255)/256, 256, 0, stream>>>(Vbf);

    for (int l = 0; l < 8; l++){
        cast_bf16_kernel<<<(TT*VPLANE + 255)/256, 256, 0, stream>>>(Xpad, Xbf);
        conv_fwd_mfma_kernel<<<dim3(4,256,1), 256, 0, stream>>>(
            Xbf, Wq + (long)l*WQ_PER_LAYER, knots + (long)l*KN*FC, Vbf);
        conv_adj_mfma_kernel<<<768, 256, 0, stream>>>(
            Vbf, Wqa + (long)l*WQA_PER_LAYER, (float*)rg);
        dc_update_kernel<<<TT*128, 256, 0, stream>>>(Xpad, mbuf, rg, G, mask, alph, moms, l);
    }

    output_kernel<<<NPIX/256, 256, 0, stream>>>(Xpad, sums, (float*)d_out);
}

// Round 14
// 1268.621 us; speedup vs baseline: 2.1696x; 2.1696x over previous
//
#include <hip/hip_runtime.h>
#include <math.h>

#define TT 6
#define FC 24
#define KN 35
#define HW 65536
#define NPIX (TT*HW)   // 393216
#define CPB 16         // columns per block in col-FFT

// padded plane geometry: 5-halo on all sides, stride 272 (16B-chunk friendly)
#define VSTRIDE 272
#define VROWS   266
#define VPLANE  (VROWS*VSTRIDE)          // 72352 elems per plane
#define VIOFF   (5*VSTRIDE + 5)          // interior origin
#define NPLANES (TT*FC)                  // 144
#define HALO_PER_PLANE 6816              // float2-plane halo positions
#define TOT_PLANES (TT + NPLANES)        // Xpad + V float2 planes, contiguous
#define NPARTS 6                         // adj channel split: 4 ch/part
#define WQ_PER_LAYER (3*11*512)          // fwd B-frags: 16896 bf16/layer

typedef float v2f __attribute__((ext_vector_type(2)));
typedef float v4f __attribute__((ext_vector_type(4)));
typedef short short8 __attribute__((ext_vector_type(8)));
typedef int  v4i  __attribute__((ext_vector_type(4)));
typedef v4i  v4i_u __attribute__((aligned(4)));   // 16B vector load, 4B alignment

__device__ inline float2 cmulf(float2 a, float2 b){
    return make_float2(a.x*b.x - a.y*b.y, a.x*b.y + a.y*b.x);
}

__device__ inline void gl_lds16(const void* g, void* l){
    __builtin_amdgcn_global_load_lds((const __attribute__((address_space(1))) unsigned int*)g,
                                     (__attribute__((address_space(3))) unsigned int*)l,
                                     16, 0, 0);
}

__device__ __host__ inline unsigned short f2bf(float x){
    unsigned u = __float_as_uint(x);
    unsigned r = (u + 0x7FFFu + ((u >> 16) & 1u)) >> 16;
    return (unsigned short)r;
}

// ---------------- halo zero: 5-wide borders of the 150 float2 planes ------------
__global__ void halo_zero_kernel(float2* base){
    int gid = blockIdx.x*256 + threadIdx.x;
    if (gid >= TOT_PLANES*HALO_PER_PLANE) return;
    int p = gid / HALO_PER_PLANE;
    int i = gid - p*HALO_PER_PLANE;
    int row, col;
    if (i < 2720){
        row = i / 272; col = i - row*272;
        if (row >= 5) row += 256;
    } else {
        int j = i - 2720;
        row = 5 + j/16;
        col = j & 15;
        if (col >= 5) col += 256;
    }
    base[(long)p*VPLANE + (long)row*VSTRIDE + col] = make_float2(0.f, 0.f);
}

// ---------------- reduction: sum|X|^2 and sum(mask) ----------------
__global__ void reduce_kernel(const float* xr, const float* xi, const float* mask, float* sums){
    __shared__ float s1[256], s2[256];
    int tid = threadIdx.x;
    int gid = blockIdx.x*256 + tid;
    float a = 0.f, b = 0.f;
    for (int i = gid; i < NPIX; i += gridDim.x*256) a += xr[i]*xr[i] + xi[i]*xi[i];
    for (int i = gid; i < TT*256; i += gridDim.x*256) b += mask[i];
    s1[tid]=a; s2[tid]=b; __syncthreads();
    for (int off=128; off>0; off>>=1){
        if (tid<off){ s1[tid]+=s1[tid+off]; s2[tid]+=s2[tid+off]; }
        __syncthreads();
    }
    if (tid==0){ atomicAdd(&sums[0], s1[0]); atomicAdd(&sums[1], s2[0]); }
}

// ---------------- normalize: Xks = (xr + i xi)/norm ----------------
__global__ void normalize_kernel(const float* xr, const float* xi, const float* sums, float2* Xks){
    int i = blockIdx.x*256 + threadIdx.x;
    float inv = rsqrtf(sums[0]/sums[1]);
    Xks[i] = make_float2(xr[i]*inv, xi[i]*inv);
}

// ---------------- adj weight repack: [l][f][tap-flipped][ri] fp32 ---------------
__global__ void repack_kernel(const float* kr, const float* ki, float* Wa){
    int i = blockIdx.x*256 + threadIdx.x;
    if (i >= 8*121*24) return;
    int f   = i % 24;
    int tap = (i/24) % 121;
    int l   = i/(24*121);
    long src = (long)(l*24+f)*121;
    Wa[(((long)l*24+f)*121+tap)*2+0] = kr[src+120-tap];   // spatial flip baked in
    Wa[(((long)l*24+f)*121+tap)*2+1] = ki[src+120-tap];
}

// ---------------- fwd MFMA weight prepack: B-frag order, bf16 -------------------
__global__ void prepack_wfrag_kernel(const float* kr, const float* ki, unsigned short* Wq){
    int idx = blockIdx.x*256 + threadIdx.x;
    if (idx >= 8*WQ_PER_LAYER) return;
    int j    = idx & 7;
    int lane = (idx >> 3) & 63;
    int ky   = (idx >> 9) % 11;
    int nt   = (idx / (512*11)) % 3;
    int l    =  idx / (512*11*3);
    int quad = lane >> 4;
    int k    = quad*8 + j;
    int part = k >> 4;
    int kx   = k & 15;
    int n    = nt*16 + (lane & 15);
    int f    = n >> 1, comp = n & 1;
    float v = 0.f;
    if (kx <= 10){
        long wi = ((long)(l*24+f))*121 + ky*11 + kx;
        float wr = kr[wi], wim = ki[wi];
        v = (comp == 0) ? (part == 0 ? wr  : -wim)
                        : (part == 0 ? wim :  wr );
    }
    Wq[idx] = f2bf(v);
}

// ---------------- FFT row pass (init only) ----------------
__global__ void fft_row_kernel(const float2* __restrict__ in, float2* __restrict__ out,
                               float dir, float scale){
    __shared__ float2 lds[2][256];
    __shared__ float2 tw[128];
    int tid = threadIdx.x;
    int line = tid >> 7;
    int j = tid & 127;
    if (tid < 128){
        float s, c;
        sincosf(dir * 6.283185307179586f * (float)tid / 256.0f, &s, &c);
        tw[tid] = make_float2(c, s);
    }
    long gline = (long)blockIdx.x*2 + line;
    const float2* src = in + gline*256;
    {
        float sg = (j & 1) ? -1.f : 1.f;
        float2 a = src[j];
        float2 b = src[j+128];
        lds[line][j]     = make_float2(a.x*sg, a.y*sg);
        lds[line][j+128] = make_float2(b.x*sg, b.y*sg);
    }
    __syncthreads();
    for (int s = 0; s < 8; s++){
        int half = 128 >> s;
        int pos = j & (half-1);
        int grp = j >> (7-s);
        int i0 = (grp << (8-s)) + pos;
        int i1 = i0 + half;
        float2 u = lds[line][i0], v = lds[line][i1];
        float2 w = tw[pos << s];
        lds[line][i0] = make_float2(u.x+v.x, u.y+v.y);
        float2 d = make_float2(u.x-v.x, u.y-v.y);
        lds[line][i1] = cmulf(d, w);
        __syncthreads();
    }
    float2* dst = out + gline*256;
    {
        int k = j;
        float sg = (k & 1) ? -scale : scale;
        float2 v = lds[line][__brev((unsigned)k) >> 24];
        dst[k] = make_float2(v.x*sg, v.y*sg);
        k = j + 128;
        sg = (k & 1) ? -scale : scale;
        v = lds[line][__brev((unsigned)k) >> 24];
        dst[k] = make_float2(v.x*sg, v.y*sg);
    }
}

// ---------------- FFT col pass (init only): writes Xpad (*k0), G, and Xbf -------
__global__ void fft_col_kernel(const float2* __restrict__ in, float2* __restrict__ Xpad,
                               float2* __restrict__ G, unsigned short* __restrict__ Xbf,
                               float dir, float scale, const float* k0){
    __shared__ float2 lds[256][CPB+1];
    __shared__ float2 tw[128];
    int tid = threadIdx.x;
    if (tid < 128){
        float s, c;
        sincosf(dir * 6.283185307179586f * (float)tid / 256.0f, &s, &c);
        tw[tid] = make_float2(c, s);
    }
    int t  = blockIdx.x / (256/CPB);
    int w0 = (blockIdx.x % (256/CPB)) * CPB;
    const float2* src = in + (long)t*HW;
    int c  = tid & (CPB-1);
    int h0 = tid >> 4;
    for (int i = 0; i < 16; i++){
        int h = h0 + 16*i;
        float2 v = src[h*256 + w0 + c];
        float sg = (h & 1) ? -1.f : 1.f;
        lds[h][c] = make_float2(v.x*sg, v.y*sg);
    }
    __syncthreads();
    int jb = tid >> 4;
    for (int s = 0; s < 8; s++){
        int half = 128 >> s;
        for (int i = 0; i < 8; i++){
            int j = jb + 16*i;
            int pos = j & (half-1);
            int grp = j >> (7-s);
            int i0 = (grp << (8-s)) + pos;
            int i1 = i0 + half;
            float2 u = lds[i0][c], v = lds[i1][c];
            float2 w = tw[pos << s];
            lds[i0][c] = make_float2(u.x+v.x, u.y+v.y);
            float2 d = make_float2(u.x-v.x, u.y-v.y);
            lds[i1][c] = cmulf(d, w);
        }
        __syncthreads();
    }
    float kk = *k0;
    for (int i = 0; i < 16; i++){
        int k = h0 + 16*i;
        float2 v = lds[__brev((unsigned)k) >> 24][c];
        float sg = (k & 1) ? -scale : scale;
        float2 g = make_float2(v.x*sg, v.y*sg);
        G[(long)t*HW + k*256 + w0 + c] = g;
        float2 x = make_float2(g.x*kk, g.y*kk);
        long off = VIOFF + (long)k*VSTRIDE + w0 + c;
        Xpad[(long)t*VPLANE + off] = x;
        unsigned short vr = f2bf(x.x), vi = f2bf(x.y);
        Xbf[((long)(0*6+t))*VPLANE + off]     = vr;
        Xbf[((long)(1*6+t))*VPLANE + off]     = vi;
        Xbf[((long)(2*6+t))*VPLANE + off - 1] = vr;   // shifted copy: c1[q] = X[q+1]
        Xbf[((long)(3*6+t))*VPLANE + off - 1] = vi;
    }
}

// ---------------- MFMA forward conv (1->24) + fused spline act ------------------
// Block: 64-pixel row segment, all 6 t, all 48 N. A from global bf16 planes,
// B (weights) from LDS frags, D in registers; writes float2 V coalesced via LDS.
__global__ __launch_bounds__(256) void conv_fwd_mfma_kernel(
        const unsigned short* __restrict__ Xbf, const unsigned short* __restrict__ Wq,
        const float* __restrict__ knots, float2* __restrict__ V){
    __shared__ __align__(16) unsigned short wlds[WQ_PER_LAYER];
    int tid = threadIdx.x;
    {
        int wv = tid >> 6, ln = tid & 63;
        #pragma unroll
        for (int r = 0; r < 9; r++){
            int c = r*256 + wv*64 + ln;
            if (c < 2112)
                gl_lds16(Wq + (long)c*8, (char*)wlds + (unsigned)(r*256 + wv*64)*16u);
        }
    }
    int h  = blockIdx.y;
    int w0 = blockIdx.x*64;
    int lane = tid & 63, wave = tid >> 6;
    int half = wave >> 1, parity = wave & 1;
    int quad = lane >> 4, l15 = lane & 15;
    int part = quad >> 1, kx0 = (quad & 1)*8;
    int col0 = half*32 + 2*l15 + kx0;

    __syncthreads();

    v4f D[3][6];
    #pragma unroll
    for (int nt = 0; nt < 3; nt++)
        #pragma unroll
        for (int t = 0; t < 6; t++) D[nt][t] = (v4f)(0.f);

    const short8* wl = (const short8*)wlds;
    #pragma unroll
    for (int t = 0; t < 6; t++){
        const unsigned short* ab = Xbf + ((long)((parity*2 + part)*6 + t))*VPLANE
                                       + (long)h*272 + w0 + col0;
        #pragma unroll
        for (int ky = 0; ky < 11; ky++){
            union { v4i i; short8 s; } ua;
            ua.i = *(const v4i_u*)(ab + (long)ky*272);
            short8 a = ua.s;
            #pragma unroll
            for (int nt = 0; nt < 3; nt++){
                short8 b = wl[(nt*11 + ky)*64 + lane];
                D[nt][t] = __builtin_amdgcn_mfma_f32_16x16x32_bf16(a, b, D[nt][t], 0, 0, 0);
            }
        }
    }

    float aout[3][4];
    #pragma unroll
    for (int nt = 0; nt < 3; nt++){
        int f = (nt*16 + l15) >> 1;
        #pragma unroll
        for (int r = 0; r < 4; r++){
            float s = 0.f;
            #pragma unroll
            for (int t = 0; t < 6; t++) s = fmaf(D[nt][t][r], D[nt][t][r], s);
            s += __shfl_xor(s, 1, 64);
            float act_in = sqrtf(s) * (1.0f/6.0f);
            float pos = fminf(fmaxf(act_in * 34.0f, 0.0f), 34.0f);
            int i0 = (int)pos; if (i0 > 33) i0 = 33;
            float frac = pos - (float)i0;
            float k0v = knots[i0*24 + f];
            float k1v = knots[(i0+1)*24 + f];
            aout[nt][r] = k0v*(1.0f - frac) + k1v*frac;
        }
    }

    float* tb = (float*)wlds;
    #pragma unroll
    for (int t = 0; t < 6; t++){
        __syncthreads();
        #pragma unroll
        for (int nt = 0; nt < 3; nt++)
            #pragma unroll
            for (int r = 0; r < 4; r++){
                int px = half*32 + 2*(quad*4 + r) + parity;
                tb[px*50 + nt*16 + l15] = D[nt][t][r] * aout[nt][r];
            }
        __syncthreads();
        #pragma unroll
        for (int q = 0; q < 6; q++){
            int idx = q*256 + tid;
            int f = idx >> 6, px = idx & 63;
            float2 val = *(const float2*)&tb[px*50 + 2*f];
            V[(long)(t*24 + f)*VPLANE + VIOFF + (long)h*VSTRIDE + (w0 + px)] = val;
        }
    }
}

// ---------------- adjoint conv 24->1: 16x64 tile, 4 rows/thread, packed fp32 -----
// z = part*6 + t ; part (0..5) handles f in [4*part, 4*part+4); writes rg + part*NPIX
__global__ __launch_bounds__(256) void conv_adj_kernel(const float2* __restrict__ V,
                                                       const float* __restrict__ wa,
                                                       float2* __restrict__ rg){
    __shared__ __align__(16) float2 vt[2][74][26];   // 2 x 15392 B, 962 chunks each
    int z = blockIdx.z;
    int t = z % 6, part = z / 6;      // part 0..5
    int h0 = blockIdx.y*64, w0 = blockIdx.x*16;
    int tx = threadIdx.x & 15;
    int r0 = (threadIdx.x >> 4) * 4;  // 0..60
    int wv = threadIdx.x >> 6, ln = threadIdx.x & 63;
    int f0 = part*4;

    const float2* gsrc[4];
    unsigned lofs[4];
    bool act[4];
    {
        const float2* plane0 = V + (long)(t*24 + f0)*VPLANE;
        #pragma unroll
        for (int r = 0; r < 4; r++){
            int s = r*256 + wv*64 + ln;
            act[r] = (s < 962);
            int row = s / 13;
            int col = s - row*13;
            gsrc[r] = plane0 + (long)(h0 + row)*VSTRIDE + w0 + col*2;
            lofs[r] = (unsigned)(r*256 + wv*64)*16u;
        }
    }
    {
        #pragma unroll
        for (int r = 0; r < 4; r++)
            if (act[r]) gl_lds16(gsrc[r], (char*)(&vt[0][0][0]) + lofs[r]);
    }
    v2f accR[4], accW[4];
    #pragma unroll
    for (int rr = 0; rr < 4; rr++){ accR[rr] = (v2f)(0.f); accW[rr] = (v2f)(0.f); }

    #pragma unroll 1
    for (int k = 0; k < 4; k++){
        int buf = k & 1;
        __syncthreads();
        if (k + 1 < 4){
            #pragma unroll
            for (int r = 0; r < 4; r++){
                if (act[r]) gl_lds16(gsrc[r] + (long)VPLANE, (char*)(&vt[buf^1][0][0]) + lofs[r]);
                gsrc[r] += VPLANE;
            }
        }
        const float* wf = wa + (f0 + k)*242;
        #pragma unroll
        for (int sr = 0; sr < 14; sr++){
            v2f v[11];
            #pragma unroll
            for (int kx = 0; kx < 11; kx++) v[kx] = *(const v2f*)&vt[buf][r0+sr][tx+kx];
            #pragma unroll
            for (int rr = 0; rr < 4; rr++){
                int ky = sr - rr;
                if (ky < 0 || ky > 10) continue;
                #pragma unroll
                for (int kx = 0; kx < 11; kx++){
                    v2f wrv = (v2f)(wf[(ky*11+kx)*2+0]);
                    v2f wiv = (v2f)(wf[(ky*11+kx)*2+1]);
                    accR[rr] = __builtin_elementwise_fma(v[kx], wrv, accR[rr]);
                    accW[rr] = __builtin_elementwise_fma(v[kx], wiv, accW[rr]);
                }
            }
        }
    }
    float2* out = rg + (long)part*NPIX + (long)t*HW;
    #pragma unroll
    for (int rr = 0; rr < 4; rr++)
        out[(long)(h0 + r0 + rr)*256 + (w0 + tx)] =
            make_float2(accR[rr].x + accW[rr].y, accR[rr].y - accW[rr].x);
}

// ---------------- fused data-consistency + momentum update + bf16 mirror --------
__global__ void dc_update_kernel(float2* __restrict__ Xpad, float2* __restrict__ m,
                                 const float2* __restrict__ rg, const float2* __restrict__ G,
                                 const float* __restrict__ mask, unsigned short* __restrict__ Xbf,
                                 const float* __restrict__ alphas, const float* __restrict__ moms,
                                 int l){
    __shared__ float2 lds[2][256];
    __shared__ float2 tw[128];
    int tid = threadIdx.x;
    int line = tid >> 7;
    int j = tid & 127;
    if (tid < 128){
        float s, c;
        sincosf(6.283185307179586f * (float)tid / 256.0f, &s, &c);
        tw[tid] = make_float2(c, s);
    }
    long gl = (long)blockIdx.x*2 + line;
    int t = (int)(gl >> 8);
    int h = (int)(gl & 255);
    float2* src = Xpad + (long)t*VPLANE + VIOFF + (long)h*VSTRIDE;
    float2 xo0, xo1;
    {
        float sg = (j & 1) ? -1.f : 1.f;
        xo0 = src[j]; xo1 = src[j+128];
        lds[line][j]     = make_float2(xo0.x*sg, xo0.y*sg);
        lds[line][j+128] = make_float2(xo1.x*sg, xo1.y*sg);
    }
    __syncthreads();
    for (int s = 0; s < 8; s++){
        int half = 128 >> s;
        int pos = j & (half-1);
        int grp = j >> (7-s);
        int i0 = (grp << (8-s)) + pos;
        int i1 = i0 + half;
        float2 u = lds[line][i0], v = lds[line][i1];
        float2 w = tw[pos << s]; w.y = -w.y;
        lds[line][i0] = make_float2(u.x+v.x, u.y+v.y);
        float2 d = make_float2(u.x-v.x, u.y-v.y);
        lds[line][i1] = cmulf(d, w);
        __syncthreads();
    }
    {
        int k1 = __brev((unsigned)j) >> 24;
        int k2 = __brev((unsigned)(j+128)) >> 24;
        float mv1 = mask[t*256 + k1] * (1.0f/256.0f);
        float mv2 = mask[t*256 + k2] * (1.0f/256.0f);
        float2 a = lds[line][j], b = lds[line][j+128];
        lds[line][j]     = make_float2(a.x*mv1, a.y*mv1);
        lds[line][j+128] = make_float2(b.x*mv2, b.y*mv2);
    }
    __syncthreads();
    for (int s = 0; s < 8; s++){
        int m2 = 1 << s;
        int pos = j & (m2-1);
        int grp = j >> s;
        int i0 = (grp << (s+1)) + pos;
        int i1 = i0 + m2;
        float2 u = lds[line][i0];
        float2 v = cmulf(lds[line][i1], tw[pos << (7-s)]);
        lds[line][i0] = make_float2(u.x+v.x, u.y+v.y);
        lds[line][i1] = make_float2(u.x-v.x, u.y-v.y);
        __syncthreads();
    }
    float a  = alphas[l];
    float mu = moms[l];
    float sg = (j & 1) ? -1.f : 1.f;
    #pragma unroll
    for (int half = 0; half < 2; half++){
        int k = j + half*128;
        long idx = gl*256 + k;
        float2 d = lds[line][k];
        d = make_float2(d.x*sg, d.y*sg);
        float2 g = G[idx];
        float rx = 0.f, ry = 0.f;
        #pragma unroll
        for (int p = 0; p < NPARTS; p++){
            float2 r = rg[idx + (long)p*NPIX];
            rx += r.x; ry += r.y;
        }
        float2 grad = make_float2(fmaf(a, d.x - g.x, rx), fmaf(a, d.y - g.y, ry));
        float2 mm;
        if (l == 0){
            mm = grad;
        } else {
            float2 mv = m[idx];
            mm = make_float2(fmaf(mu, mv.x, grad.x), fmaf(mu, mv.y, grad.y));
        }
        m[idx] = mm;
        float2 xo = half ? xo1 : xo0;
        float2 nv = make_float2(xo.x - mm.x, xo.y - mm.y);
        src[k] = nv;
        // bf16 mirror for the next layer's MFMA forward (copy1 shifted by -1)
        long off = VIOFF + (long)h*VSTRIDE + k;
        unsigned short vr = f2bf(nv.x), vi = f2bf(nv.y);
        Xbf[((long)(0*6+t))*VPLANE + off]     = vr;
        Xbf[((long)(1*6+t))*VPLANE + off]     = vi;
        Xbf[((long)(2*6+t))*VPLANE + off - 1] = vr;
        Xbf[((long)(3*6+t))*VPLANE + off - 1] = vi;
    }
}

// ---------------- output: stack(real, imag)*norm ----------------
__global__ void output_kernel(const float2* __restrict__ Xpad, const float* __restrict__ sums,
                              float* __restrict__ out){
    int i = blockIdx.x*256 + threadIdx.x;
    int t = i >> 16;
    int p = i & 65535;
    int h = p >> 8, w = p & 255;
    float norm = sqrtf(sums[0]/sums[1]);
    float2 v = Xpad[(long)t*VPLANE + VIOFF + h*VSTRIDE + w];
    out[2*i]   = v.x * norm;
    out[2*i+1] = v.y * norm;
}

extern "C" void kernel_launch(void* const* d_in, const int* in_sizes, int n_in,
                              void* d_out, int out_size, void* d_ws, size_t ws_size,
                              hipStream_t stream){
    const float* Xr    = (const float*)d_in[0];
    const float* Xi    = (const float*)d_in[1];
    const float* mask  = (const float*)d_in[2];
    const float* kr    = (const float*)d_in[3];
    const float* ki    = (const float*)d_in[4];
    const float* knots = (const float*)d_in[5];
    const float* alph  = (const float*)d_in[6];
    const float* moms  = (const float*)d_in[7];
    const float* k0    = (const float*)d_in[8];

    float* ws   = (float*)d_ws;
    float* sums = ws;                                          // 16 floats
    float* Wa   = ws + 16;                                     // 8*121*48 floats
    unsigned short* Wq  = (unsigned short*)(Wa + 8*121*48);    // 8*16896 bf16
    unsigned short* Xbf = Wq + 8*WQ_PER_LAYER;                 // 24*VPLANE bf16
    float2* mbuf = (float2*)(Xbf + 24*VPLANE);
    float2* G    = mbuf + NPIX;
    float2* rg   = G    + NPIX;                                // NPARTS*NPIX; [0] also init tmp
    float2* Xpad = rg   + NPARTS*NPIX;                         // 6*VPLANE float2
    float2* V    = Xpad + TT*VPLANE;                           // 144*VPLANE float2
    float2* Xks  = V;                                          // init-only alias

    const float OS = 1.0f/16.0f;

    hipMemsetAsync(sums, 0, 2*sizeof(float), stream);
    hipMemsetAsync(Xbf, 0, (size_t)24*VPLANE*sizeof(unsigned short), stream);  // zero bf16 halos

    repack_kernel<<<(8*121*24 + 255)/256, 256, 0, stream>>>(kr, ki, Wa);
    prepack_wfrag_kernel<<<(8*WQ_PER_LAYER + 255)/256, 256, 0, stream>>>(kr, ki, Wq);
    reduce_kernel<<<384, 256, 0, stream>>>(Xr, Xi, mask, sums);
    normalize_kernel<<<NPIX/256, 256, 0, stream>>>(Xr, Xi, sums, Xks);

    // init: Xpad = k2i(Xks)*k0 (padded, + bf16 mirror) ; G = k2i(Xks)
    fft_row_kernel<<<TT*128, 256, 0, stream>>>(Xks, rg, +1.0f, OS);
    fft_col_kernel<<<TT*(256/CPB), 256, 0, stream>>>(rg, Xpad, G, Xbf, +1.0f, OS, k0);

    // zero float2-plane halos AFTER init (Xks alias in V region is dead now)
    halo_zero_kernel<<<(TOT_PLANES*HALO_PER_PLANE + 255)/256, 256, 0, stream>>>(Xpad);

    for (int l = 0; l < 8; l++){
        conv_fwd_mfma_kernel<<<dim3(4,256,1), 256, 0, stream>>>(
            Xbf, Wq + (long)l*WQ_PER_LAYER, knots + (long)l*KN*FC, V);
        conv_adj_kernel<<<dim3(16,4,NPARTS*TT), 256, 0, stream>>>(V, Wa + (long)l*24*242, rg);
        dc_update_kernel<<<TT*128, 256, 0, stream>>>(Xpad, mbuf, rg, G, mask, Xbf, alph, moms, l);
    }

    output_kernel<<<NPIX/256, 256, 0, stream>>>(Xpad, sums, (float*)d_out);
}

// Round 15
// 1017.477 us; speedup vs baseline: 2.7051x; 1.2468x over previous
//
#include <hip/hip_runtime.h>
#include <math.h>

#define TT 6
#define FC 24
#define KN 35
#define HW 65536
#define NPIX (TT*HW)   // 393216
#define CPB 16         // columns per block in col-FFT

// padded plane geometry: 5-halo on all sides, stride 272 (16B-chunk friendly)
#define VSTRIDE 272
#define VROWS   266
#define VPLANE  (VROWS*VSTRIDE)          // 72352 elems per plane
#define VIOFF   (5*VSTRIDE + 5)          // interior origin
#define NPLANES (TT*FC)                  // 144
#define HALO_PER_PLANE 6816              // halo positions per plane
#define NPARTS 4                         // adj channel split: 6 ch/part
#define WQ_PER_LAYER (3*11*512)          // fwd B-frags: 16896 bf16/layer
#define WD_PER_LAYER (24*121*2)          // adj dot2 weights: 5808 uints/layer
#define ACH 518                          // adj staged chunks per channel (74 rows x 7)

typedef float v2f __attribute__((ext_vector_type(2)));
typedef float v4f __attribute__((ext_vector_type(4)));
typedef short short8 __attribute__((ext_vector_type(8)));
typedef _Float16 half2_t __attribute__((ext_vector_type(2)));
typedef int  v4i  __attribute__((ext_vector_type(4)));
typedef v4i  v4i_u __attribute__((aligned(4)));   // 16B vector load, 4B alignment

__device__ inline float2 cmulf(float2 a, float2 b){
    return make_float2(a.x*b.x - a.y*b.y, a.x*b.y + a.y*b.x);
}

__device__ inline void gl_lds16(const void* g, void* l){
    __builtin_amdgcn_global_load_lds((const __attribute__((address_space(1))) unsigned int*)g,
                                     (__attribute__((address_space(3))) unsigned int*)l,
                                     16, 0, 0);
}

__device__ __host__ inline unsigned short f2bf(float x){
    unsigned u = __float_as_uint(x);
    unsigned r = (u + 0x7FFFu + ((u >> 16) & 1u)) >> 16;
    return (unsigned short)r;
}

// ---------------- halo zero: 5-wide borders of the 6 float2 Xpad planes ---------
__global__ void halo_zero_kernel(float2* base){
    int gid = blockIdx.x*256 + threadIdx.x;
    if (gid >= TT*HALO_PER_PLANE) return;
    int p = gid / HALO_PER_PLANE;
    int i = gid - p*HALO_PER_PLANE;
    int row, col;
    if (i < 2720){
        row = i / 272; col = i - row*272;
        if (row >= 5) row += 256;
    } else {
        int j = i - 2720;
        row = 5 + j/16;
        col = j & 15;
        if (col >= 5) col += 256;
    }
    base[(long)p*VPLANE + (long)row*VSTRIDE + col] = make_float2(0.f, 0.f);
}

// ---------------- halo zero: borders of the 144 uint (f16x2) V planes -----------
__global__ void halo_zero_vh_kernel(unsigned int* base){
    int gid = blockIdx.x*256 + threadIdx.x;
    if (gid >= NPLANES*HALO_PER_PLANE) return;
    int p = gid / HALO_PER_PLANE;
    int i = gid - p*HALO_PER_PLANE;
    int row, col;
    if (i < 2720){
        row = i / 272; col = i - row*272;
        if (row >= 5) row += 256;
    } else {
        int j = i - 2720;
        row = 5 + j/16;
        col = j & 15;
        if (col >= 5) col += 256;
    }
    base[(long)p*VPLANE + (long)row*VSTRIDE + col] = 0u;
}

// ---------------- reduction: sum|X|^2 and sum(mask) ----------------
__global__ void reduce_kernel(const float* xr, const float* xi, const float* mask, float* sums){
    __shared__ float s1[256], s2[256];
    int tid = threadIdx.x;
    int gid = blockIdx.x*256 + tid;
    float a = 0.f, b = 0.f;
    for (int i = gid; i < NPIX; i += gridDim.x*256) a += xr[i]*xr[i] + xi[i]*xi[i];
    for (int i = gid; i < TT*256; i += gridDim.x*256) b += mask[i];
    s1[tid]=a; s2[tid]=b; __syncthreads();
    for (int off=128; off>0; off>>=1){
        if (tid<off){ s1[tid]+=s1[tid+off]; s2[tid]+=s2[tid+off]; }
        __syncthreads();
    }
    if (tid==0){ atomicAdd(&sums[0], s1[0]); atomicAdd(&sums[1], s2[0]); }
}

// ---------------- normalize: Xks = (xr + i xi)/norm ----------------
__global__ void normalize_kernel(const float* xr, const float* xi, const float* sums, float2* Xks){
    int i = blockIdx.x*256 + threadIdx.x;
    float inv = rsqrtf(sums[0]/sums[1]);
    Xks[i] = make_float2(xr[i]*inv, xi[i]*inv);
}

// ---------------- fwd MFMA weight prepack: B-frag order, bf16 -------------------
__global__ void prepack_wfrag_kernel(const float* kr, const float* ki, unsigned short* Wq){
    int idx = blockIdx.x*256 + threadIdx.x;
    if (idx >= 8*WQ_PER_LAYER) return;
    int j    = idx & 7;
    int lane = (idx >> 3) & 63;
    int ky   = (idx >> 9) % 11;
    int nt   = (idx / (512*11)) % 3;
    int l    =  idx / (512*11*3);
    int quad = lane >> 4;
    int k    = quad*8 + j;
    int part = k >> 4;
    int kx   = k & 15;
    int n    = nt*16 + (lane & 15);
    int f    = n >> 1, comp = n & 1;
    float v = 0.f;
    if (kx <= 10){
        long wi = ((long)(l*24+f))*121 + ky*11 + kx;
        float wr = kr[wi], wim = ki[wi];
        v = (comp == 0) ? (part == 0 ? wr  : -wim)
                        : (part == 0 ? wim :  wr );
    }
    Wq[idx] = f2bf(v);
}

// ---------------- adj dot2 weight prepack: [l][f][tap-flipped][c] f16x2 ---------
// c=0 -> (wr, wi) for out.r ; c=1 -> (-wi, wr) for out.i
__global__ void prepack_wdot_kernel(const float* kr, const float* ki, unsigned int* Wd){
    int idx = blockIdx.x*256 + threadIdx.x;
    if (idx >= 8*WD_PER_LAYER) return;
    int c   = idx & 1;
    int tap = (idx >> 1) % 121;
    int f   = ((idx >> 1) / 121) % 24;
    int l   = (idx >> 1) / (121*24);
    long src = (long)(l*24+f)*121 + (120 - tap);   // spatial flip baked in
    float wr = kr[src], wi = ki[src];
    half2_t h;
    if (c == 0){ h[0] = (_Float16)wr;  h[1] = (_Float16)wi; }
    else       { h[0] = (_Float16)(-wi); h[1] = (_Float16)wr; }
    Wd[idx] = *(unsigned int*)&h;
}

// ---------------- FFT row pass (init only) ----------------
__global__ void fft_row_kernel(const float2* __restrict__ in, float2* __restrict__ out,
                               float dir, float scale){
    __shared__ float2 lds[2][256];
    __shared__ float2 tw[128];
    int tid = threadIdx.x;
    int line = tid >> 7;
    int j = tid & 127;
    if (tid < 128){
        float s, c;
        sincosf(dir * 6.283185307179586f * (float)tid / 256.0f, &s, &c);
        tw[tid] = make_float2(c, s);
    }
    long gline = (long)blockIdx.x*2 + line;
    const float2* src = in + gline*256;
    {
        float sg = (j & 1) ? -1.f : 1.f;
        float2 a = src[j];
        float2 b = src[j+128];
        lds[line][j]     = make_float2(a.x*sg, a.y*sg);
        lds[line][j+128] = make_float2(b.x*sg, b.y*sg);
    }
    __syncthreads();
    for (int s = 0; s < 8; s++){
        int half = 128 >> s;
        int pos = j & (half-1);
        int grp = j >> (7-s);
        int i0 = (grp << (8-s)) + pos;
        int i1 = i0 + half;
        float2 u = lds[line][i0], v = lds[line][i1];
        float2 w = tw[pos << s];
        lds[line][i0] = make_float2(u.x+v.x, u.y+v.y);
        float2 d = make_float2(u.x-v.x, u.y-v.y);
        lds[line][i1] = cmulf(d, w);
        __syncthreads();
    }
    float2* dst = out + gline*256;
    {
        int k = j;
        float sg = (k & 1) ? -scale : scale;
        float2 v = lds[line][__brev((unsigned)k) >> 24];
        dst[k] = make_float2(v.x*sg, v.y*sg);
        k = j + 128;
        sg = (k & 1) ? -scale : scale;
        v = lds[line][__brev((unsigned)k) >> 24];
        dst[k] = make_float2(v.x*sg, v.y*sg);
    }
}

// ---------------- FFT col pass (init only): writes Xpad (*k0), G, and Xbf -------
__global__ void fft_col_kernel(const float2* __restrict__ in, float2* __restrict__ Xpad,
                               float2* __restrict__ G, unsigned short* __restrict__ Xbf,
                               float dir, float scale, const float* k0){
    __shared__ float2 lds[256][CPB+1];
    __shared__ float2 tw[128];
    int tid = threadIdx.x;
    if (tid < 128){
        float s, c;
        sincosf(dir * 6.283185307179586f * (float)tid / 256.0f, &s, &c);
        tw[tid] = make_float2(c, s);
    }
    int t  = blockIdx.x / (256/CPB);
    int w0 = (blockIdx.x % (256/CPB)) * CPB;
    const float2* src = in + (long)t*HW;
    int c  = tid & (CPB-1);
    int h0 = tid >> 4;
    for (int i = 0; i < 16; i++){
        int h = h0 + 16*i;
        float2 v = src[h*256 + w0 + c];
        float sg = (h & 1) ? -1.f : 1.f;
        lds[h][c] = make_float2(v.x*sg, v.y*sg);
    }
    __syncthreads();
    int jb = tid >> 4;
    for (int s = 0; s < 8; s++){
        int half = 128 >> s;
        for (int i = 0; i < 8; i++){
            int j = jb + 16*i;
            int pos = j & (half-1);
            int grp = j >> (7-s);
            int i0 = (grp << (8-s)) + pos;
            int i1 = i0 + half;
            float2 u = lds[i0][c], v = lds[i1][c];
            float2 w = tw[pos << s];
            lds[i0][c] = make_float2(u.x+v.x, u.y+v.y);
            float2 d = make_float2(u.x-v.x, u.y-v.y);
            lds[i1][c] = cmulf(d, w);
        }
        __syncthreads();
    }
    float kk = *k0;
    for (int i = 0; i < 16; i++){
        int k = h0 + 16*i;
        float2 v = lds[__brev((unsigned)k) >> 24][c];
        float sg = (k & 1) ? -scale : scale;
        float2 g = make_float2(v.x*sg, v.y*sg);
        G[(long)t*HW + k*256 + w0 + c] = g;
        float2 x = make_float2(g.x*kk, g.y*kk);
        long off = VIOFF + (long)k*VSTRIDE + w0 + c;
        Xpad[(long)t*VPLANE + off] = x;
        unsigned short vr = f2bf(x.x), vi = f2bf(x.y);
        Xbf[((long)(0*6+t))*VPLANE + off]     = vr;
        Xbf[((long)(1*6+t))*VPLANE + off]     = vi;
        Xbf[((long)(2*6+t))*VPLANE + off - 1] = vr;   // shifted copy: c1[q] = X[q+1]
        Xbf[((long)(3*6+t))*VPLANE + off - 1] = vi;
    }
}

// ---------------- MFMA forward conv (1->24) + fused spline act ------------------
// Block: 64-pixel row segment, all 6 t, all 48 N. Writes V as f16x2 (uint) planes.
__global__ __launch_bounds__(256) void conv_fwd_mfma_kernel(
        const unsigned short* __restrict__ Xbf, const unsigned short* __restrict__ Wq,
        const float* __restrict__ knots, unsigned int* __restrict__ Vh){
    __shared__ __align__(16) unsigned short wlds[WQ_PER_LAYER];
    int tid = threadIdx.x;
    {
        int wv = tid >> 6, ln = tid & 63;
        #pragma unroll
        for (int r = 0; r < 9; r++){
            int c = r*256 + wv*64 + ln;
            if (c < 2112)
                gl_lds16(Wq + (long)c*8, (char*)wlds + (unsigned)(r*256 + wv*64)*16u);
        }
    }
    int h  = blockIdx.y;
    int w0 = blockIdx.x*64;
    int lane = tid & 63, wave = tid >> 6;
    int half = wave >> 1, parity = wave & 1;
    int quad = lane >> 4, l15 = lane & 15;
    int part = quad >> 1, kx0 = (quad & 1)*8;
    int col0 = half*32 + 2*l15 + kx0;

    __syncthreads();

    v4f D[3][6];
    #pragma unroll
    for (int nt = 0; nt < 3; nt++)
        #pragma unroll
        for (int t = 0; t < 6; t++) D[nt][t] = (v4f)(0.f);

    const short8* wl = (const short8*)wlds;
    #pragma unroll
    for (int t = 0; t < 6; t++){
        const unsigned short* ab = Xbf + ((long)((parity*2 + part)*6 + t))*VPLANE
                                       + (long)h*272 + w0 + col0;
        #pragma unroll
        for (int ky = 0; ky < 11; ky++){
            union { v4i i; short8 s; } ua;
            ua.i = *(const v4i_u*)(ab + (long)ky*272);
            short8 a = ua.s;
            #pragma unroll
            for (int nt = 0; nt < 3; nt++){
                short8 b = wl[(nt*11 + ky)*64 + lane];
                D[nt][t] = __builtin_amdgcn_mfma_f32_16x16x32_bf16(a, b, D[nt][t], 0, 0, 0);
            }
        }
    }

    float aout[3][4];
    #pragma unroll
    for (int nt = 0; nt < 3; nt++){
        int f = (nt*16 + l15) >> 1;
        #pragma unroll
        for (int r = 0; r < 4; r++){
            float s = 0.f;
            #pragma unroll
            for (int t = 0; t < 6; t++) s = fmaf(D[nt][t][r], D[nt][t][r], s);
            s += __shfl_xor(s, 1, 64);
            float act_in = sqrtf(s) * (1.0f/6.0f);
            float pos = fminf(fmaxf(act_in * 34.0f, 0.0f), 34.0f);
            int i0 = (int)pos; if (i0 > 33) i0 = 33;
            float frac = pos - (float)i0;
            float k0v = knots[i0*24 + f];
            float k1v = knots[(i0+1)*24 + f];
            aout[nt][r] = k0v*(1.0f - frac) + k1v*frac;
        }
    }

    float* tb = (float*)wlds;
    #pragma unroll
    for (int t = 0; t < 6; t++){
        __syncthreads();
        #pragma unroll
        for (int nt = 0; nt < 3; nt++)
            #pragma unroll
            for (int r = 0; r < 4; r++){
                int px = half*32 + 2*(quad*4 + r) + parity;
                tb[px*50 + nt*16 + l15] = D[nt][t][r] * aout[nt][r];
            }
        __syncthreads();
        #pragma unroll
        for (int q = 0; q < 6; q++){
            int idx = q*256 + tid;
            int f = idx >> 6, px = idx & 63;
            float2 val = *(const float2*)&tb[px*50 + 2*f];
            half2_t hv; hv[0] = (_Float16)val.x; hv[1] = (_Float16)val.y;
            Vh[(long)(t*24 + f)*VPLANE + VIOFF + (long)h*VSTRIDE + (w0 + px)] =
                *(unsigned int*)&hv;
        }
    }
}

// ---------------- adjoint conv 24->1: f16x2 V + v_dot2_f32_f16 ------------------
// 16x64 tile, 4 rows/thread; LDS tile 74 rows x 28 uints (f16x2 pixels), staged via
// global_load_lds (7 x 16B chunks/row, padded-coord base w0 -> 16B aligned).
// z = part*6 + t ; part (0..3) handles f in [6*part, 6*part+6); writes rg + part*NPIX
__global__ __launch_bounds__(256) void conv_adj_kernel(const unsigned int* __restrict__ Vh,
                                                       const unsigned int* __restrict__ Wd,
                                                       float2* __restrict__ rg){
    __shared__ __align__(16) unsigned int vt[2][74*28];   // 2 x 8288 B
    int z = blockIdx.z;
    int t = z % 6, part = z / 6;      // part 0..3
    int h0 = blockIdx.y*64, w0 = blockIdx.x*16;
    int tx = threadIdx.x & 15;
    int r0 = (threadIdx.x >> 4) * 4;  // 0..60
    int wv = threadIdx.x >> 6, ln = threadIdx.x & 63;
    int f0 = part*6;

    const unsigned int* gsrc[3];
    unsigned lofs[3];
    bool act[3];
    {
        const unsigned int* plane0 = Vh + (long)(t*24 + f0)*VPLANE;
        #pragma unroll
        for (int r = 0; r < 3; r++){
            int s = r*256 + wv*64 + ln;
            act[r] = (s < ACH);
            int row = s / 7;
            int col = s - row*7;
            gsrc[r] = plane0 + (long)(h0 + row)*VSTRIDE + w0 + col*4;   // padded coords
            lofs[r] = (unsigned)(r*256 + wv*64)*16u;
        }
    }
    {   // prologue: stage channel f0 into buf 0
        #pragma unroll
        for (int r = 0; r < 3; r++)
            if (act[r]) gl_lds16(gsrc[r], (char*)(&vt[0][0]) + lofs[r]);
    }
    float accR[4], accI[4];
    #pragma unroll
    for (int rr = 0; rr < 4; rr++){ accR[rr] = 0.f; accI[rr] = 0.f; }

    #pragma unroll 1
    for (int k = 0; k < 6; k++){
        int buf = k & 1;
        __syncthreads();   // drains vmcnt -> vt[buf] complete; prior readers of vt[buf^1] done
        if (k + 1 < 6){    // async-stage next channel into the other buffer
            #pragma unroll
            for (int r = 0; r < 3; r++){
                if (act[r]) gl_lds16(gsrc[r] + (long)VPLANE, (char*)(&vt[buf^1][0]) + lofs[r]);
                gsrc[r] += VPLANE;
            }
        }
        const unsigned int* wd = Wd + (long)(f0 + k)*242;
        const unsigned int* vb = &vt[buf][0];
        #pragma unroll
        for (int sr = 0; sr < 14; sr++){
            int base = (r0 + sr)*28 + tx;
            half2_t u[11];
            #pragma unroll
            for (int j = 0; j < 11; j++){
                unsigned int uv = vb[base + j];
                u[j] = *(half2_t*)&uv;
            }
            #pragma unroll
            for (int rr = 0; rr < 4; rr++){
                int ky = sr - rr;
                if (ky < 0 || ky > 10) continue;   // compile-time resolved
                const unsigned int* wk = wd + ky*22;
                #pragma unroll
                for (int kx = 0; kx < 11; kx++){
                    unsigned int wr_ = wk[kx*2+0];
                    unsigned int wi_ = wk[kx*2+1];
                    accR[rr] = __builtin_amdgcn_fdot2(u[kx], *(half2_t*)&wr_, accR[rr], false);
                    accI[rr] = __builtin_amdgcn_fdot2(u[kx], *(half2_t*)&wi_, accI[rr], false);
                }
            }
        }
    }
    float2* out = rg + (long)part*NPIX + (long)t*HW;
    #pragma unroll
    for (int rr = 0; rr < 4; rr++)
        out[(long)(h0 + r0 + rr)*256 + (w0 + tx)] = make_float2(accR[rr], accI[rr]);
}

// ---------------- fused data-consistency + momentum update + bf16 mirror --------
__global__ void dc_update_kernel(float2* __restrict__ Xpad, float2* __restrict__ m,
                                 const float2* __restrict__ rg, const float2* __restrict__ G,
                                 const float* __restrict__ mask, unsigned short* __restrict__ Xbf,
                                 const float* __restrict__ alphas, const float* __restrict__ moms,
                                 int l){
    __shared__ float2 lds[2][256];
    __shared__ float2 tw[128];
    int tid = threadIdx.x;
    int line = tid >> 7;
    int j = tid & 127;
    if (tid < 128){
        float s, c;
        sincosf(6.283185307179586f * (float)tid / 256.0f, &s, &c);
        tw[tid] = make_float2(c, s);
    }
    long gl = (long)blockIdx.x*2 + line;
    int t = (int)(gl >> 8);
    int h = (int)(gl & 255);
    float2* src = Xpad + (long)t*VPLANE + VIOFF + (long)h*VSTRIDE;
    float2 xo0, xo1;
    {
        float sg = (j & 1) ? -1.f : 1.f;
        xo0 = src[j]; xo1 = src[j+128];
        lds[line][j]     = make_float2(xo0.x*sg, xo0.y*sg);
        lds[line][j+128] = make_float2(xo1.x*sg, xo1.y*sg);
    }
    __syncthreads();
    for (int s = 0; s < 8; s++){
        int half = 128 >> s;
        int pos = j & (half-1);
        int grp = j >> (7-s);
        int i0 = (grp << (8-s)) + pos;
        int i1 = i0 + half;
        float2 u = lds[line][i0], v = lds[line][i1];
        float2 w = tw[pos << s]; w.y = -w.y;
        lds[line][i0] = make_float2(u.x+v.x, u.y+v.y);
        float2 d = make_float2(u.x-v.x, u.y-v.y);
        lds[line][i1] = cmulf(d, w);
        __syncthreads();
    }
    {
        int k1 = __brev((unsigned)j) >> 24;
        int k2 = __brev((unsigned)(j+128)) >> 24;
        float mv1 = mask[t*256 + k1] * (1.0f/256.0f);
        float mv2 = mask[t*256 + k2] * (1.0f/256.0f);
        float2 a = lds[line][j], b = lds[line][j+128];
        lds[line][j]     = make_float2(a.x*mv1, a.y*mv1);
        lds[line][j+128] = make_float2(b.x*mv2, b.y*mv2);
    }
    __syncthreads();
    for (int s = 0; s < 8; s++){
        int m2 = 1 << s;
        int pos = j & (m2-1);
        int grp = j >> s;
        int i0 = (grp << (s+1)) + pos;
        int i1 = i0 + m2;
        float2 u = lds[line][i0];
        float2 v = cmulf(lds[line][i1], tw[pos << (7-s)]);
        lds[line][i0] = make_float2(u.x+v.x, u.y+v.y);
        lds[line][i1] = make_float2(u.x-v.x, u.y-v.y);
        __syncthreads();
    }
    float a  = alphas[l];
    float mu = moms[l];
    float sg = (j & 1) ? -1.f : 1.f;
    #pragma unroll
    for (int half = 0; half < 2; half++){
        int k = j + half*128;
        long idx = gl*256 + k;
        float2 d = lds[line][k];
        d = make_float2(d.x*sg, d.y*sg);
        float2 g = G[idx];
        float rx = 0.f, ry = 0.f;
        #pragma unroll
        for (int p = 0; p < NPARTS; p++){
            float2 r = rg[idx + (long)p*NPIX];
            rx += r.x; ry += r.y;
        }
        float2 grad = make_float2(fmaf(a, d.x - g.x, rx), fmaf(a, d.y - g.y, ry));
        float2 mm;
        if (l == 0){
            mm = grad;
        } else {
            float2 mv = m[idx];
            mm = make_float2(fmaf(mu, mv.x, grad.x), fmaf(mu, mv.y, grad.y));
        }
        m[idx] = mm;
        float2 xo = half ? xo1 : xo0;
        float2 nv = make_float2(xo.x - mm.x, xo.y - mm.y);
        src[k] = nv;
        long off = VIOFF + (long)h*VSTRIDE + k;
        unsigned short vr = f2bf(nv.x), vi = f2bf(nv.y);
        Xbf[((long)(0*6+t))*VPLANE + off]     = vr;
        Xbf[((long)(1*6+t))*VPLANE + off]     = vi;
        Xbf[((long)(2*6+t))*VPLANE + off - 1] = vr;
        Xbf[((long)(3*6+t))*VPLANE + off - 1] = vi;
    }
}

// ---------------- output: stack(real, imag)*norm ----------------
__global__ void output_kernel(const float2* __restrict__ Xpad, const float* __restrict__ sums,
                              float* __restrict__ out){
    int i = blockIdx.x*256 + threadIdx.x;
    int t = i >> 16;
    int p = i & 65535;
    int h = p >> 8, w = p & 255;
    float norm = sqrtf(sums[0]/sums[1]);
    float2 v = Xpad[(long)t*VPLANE + VIOFF + h*VSTRIDE + w];
    out[2*i]   = v.x * norm;
    out[2*i+1] = v.y * norm;
}

extern "C" void kernel_launch(void* const* d_in, const int* in_sizes, int n_in,
                              void* d_out, int out_size, void* d_ws, size_t ws_size,
                              hipStream_t stream){
    const float* Xr    = (const float*)d_in[0];
    const float* Xi    = (const float*)d_in[1];
    const float* mask  = (const float*)d_in[2];
    const float* kr    = (const float*)d_in[3];
    const float* ki    = (const float*)d_in[4];
    const float* knots = (const float*)d_in[5];
    const float* alph  = (const float*)d_in[6];
    const float* moms  = (const float*)d_in[7];
    const float* k0    = (const float*)d_in[8];

    float* ws   = (float*)d_ws;
    float* sums = ws;                                          // 16 floats
    unsigned int*   Wd  = (unsigned int*)(ws + 16);            // 8*5808 uints
    unsigned short* Wq  = (unsigned short*)(Wd + 8*WD_PER_LAYER);  // 8*16896 bf16
    unsigned short* Xbf = Wq + 8*WQ_PER_LAYER;                 // 24*VPLANE bf16
    float2* mbuf = (float2*)(Xbf + 24*VPLANE);
    float2* G    = mbuf + NPIX;
    float2* rg   = G    + NPIX;                                // NPARTS*NPIX; [0] also init tmp
    float2* Xpad = rg   + NPARTS*NPIX;                         // 6*VPLANE float2
    unsigned int* Vh = (unsigned int*)(Xpad + TT*VPLANE);      // 144*VPLANE uint (f16x2)
    float2* Xks  = (float2*)Vh;                                // init-only alias

    const float OS = 1.0f/16.0f;

    hipMemsetAsync(sums, 0, 2*sizeof(float), stream);
    hipMemsetAsync(Xbf, 0, (size_t)24*VPLANE*sizeof(unsigned short), stream);  // bf16 halos

    prepack_wfrag_kernel<<<(8*WQ_PER_LAYER + 255)/256, 256, 0, stream>>>(kr, ki, Wq);
    prepack_wdot_kernel<<<(8*WD_PER_LAYER + 255)/256, 256, 0, stream>>>(kr, ki, Wd);
    reduce_kernel<<<384, 256, 0, stream>>>(Xr, Xi, mask, sums);
    normalize_kernel<<<NPIX/256, 256, 0, stream>>>(Xr, Xi, sums, Xks);

    // init: Xpad = k2i(Xks)*k0 (padded, + bf16 mirror) ; G = k2i(Xks)
    fft_row_kernel<<<TT*128, 256, 0, stream>>>(Xks, rg, +1.0f, OS);
    fft_col_kernel<<<TT*(256/CPB), 256, 0, stream>>>(rg, Xpad, G, Xbf, +1.0f, OS, k0);

    // zero halos AFTER init (Xks alias in Vh region is dead now)
    halo_zero_kernel<<<(TT*HALO_PER_PLANE + 255)/256, 256, 0, stream>>>(Xpad);
    halo_zero_vh_kernel<<<(NPLANES*HALO_PER_PLANE + 255)/256, 256, 0, stream>>>(Vh);

    for (int l = 0; l < 8; l++){
        conv_fwd_mfma_kernel<<<dim3(4,256,1), 256, 0, stream>>>(
            Xbf, Wq + (long)l*WQ_PER_LAYER, knots + (long)l*KN*FC, Vh);
        conv_adj_kernel<<<dim3(16,4,NPARTS*TT), 256, 0, stream>>>(
            Vh, Wd + (long)l*WD_PER_LAYER, rg);
        dc_update_kernel<<<TT*128, 256, 0, stream>>>(Xpad, mbuf, rg, G, mask, Xbf, alph, moms, l);
    }

    output_kernel<<<NPIX/256, 256, 0, stream>>>(Xpad, sums, (float*)d_out);
}